// Round 13
// baseline (107.385 us; speedup 1.0000x reference)
//
#include <hip/hip_runtime.h>
#include <hip/hip_bf16.h>

// Deformable conv2d (v1, align_corners=True, zeros padding), bf16 MFMA.
// R13 = R10 main (best measured) with the NCHW->NHWC-bf16 prep FUSED into the
// main kernel: each block builds its 14x16-pixel LDS tile directly from NCHW
// fp32 x (transpose folded into the XOR-swizzled ds_write pattern). Removes
// the xT dispatch, its stream-serialization gap, and a 8.4MB write + 8.4MB
// read round-trip. Only the 73KB weight-fragment repack remains as a tiny
// prep kernel. Compute loop identical to R10.
// x(4,64,128,128) f32, offset(4,18,128,128) f32, weight(64,64,9) f32
// -> out(4,64,128,128) f32.  iy = oh + off_y, ix = ow + off_x.

#define NB 4
#define CI 64
#define HH 128
#define WW 128
#define OCH 64
#define KNN 9
#define HW (HH * WW)

typedef unsigned int u32;
typedef unsigned short u16;
typedef __attribute__((ext_vector_type(8))) short bf16x8;
typedef __attribute__((ext_vector_type(4))) float f32x4;

__device__ inline u16 f2bf(float f) {  // RNE
    u32 u = __float_as_uint(f);
    return (u16)((u + 0x7fffu + ((u >> 16) & 1u)) >> 16);
}
__device__ inline u32 pk2(float lo, float hi) {
    return (u32)f2bf(lo) | ((u32)f2bf(hi) << 16);
}
__device__ inline float2 up2v(u32 u) {
    return float2{__uint_as_float(u << 16), __uint_as_float(u & 0xffff0000u)};
}
__device__ inline u32 pkrn(float2 s) {
    union { __hip_bfloat162 b; u32 u; } c;
    c.b = __float22bfloat162_rn(s);
    return c.u;
}

// ---- tiny prep: weight (OC,C,KN) f32 -> A-fragment order bf16.
// wf layout: frag[kn][chunk(2)][strip(4)][lane(64)][j(8)]; lane holds
// A[m=lane&15][k=(lane>>4)*8+j], oc = strip*16+m, c = chunk*32+k.
__global__ __launch_bounds__(256) void wf_prep_kernel(const float* __restrict__ w,
                                                      u16* __restrict__ wf) {
    int i = blockIdx.x * 256 + threadIdx.x;
    if (i < KNN * 2 * 4 * 64 * 8) {
        int j = i & 7, l = (i >> 3) & 63, strip = (i >> 9) & 3,
            chunk = (i >> 11) & 1, kn = i >> 12;
        int oc = strip * 16 + (l & 15);
        int c = chunk * 32 + ((l >> 4) & 3) * 8 + j;
        wf[i] = f2bf(w[(oc * CI + c) * KNN + kn]);
    }
}

// ---- main kernel: block = 8x8 patch (4 waves of 4x4), 64 oc, fused tile load.
__global__ __launch_bounds__(256, 4) void dcn_main_kernel(const float* __restrict__ x,
                                                          const float* __restrict__ off,
                                                          const u16* __restrict__ wf,
                                                          float* __restrict__ out) {
    // 14x16 pixels x 64ch bf16; pixel row = 32 dw (128B); chunk q at q^(p&7).
    __shared__ __align__(16) u32 tile[224 * 32];  // 28,672 B
    const int tid = threadIdx.x;
    const int l = tid & 63;
    const int wv = tid >> 6;

    // XCD-affine decode: xcd = blockIdx&7; n = xcd>>1; half = xcd&1.
    const int b = blockIdx.x;
    const int xcd = b & 7;
    const int n = xcd >> 1;
    const int patch = (b >> 3) + ((xcd & 1) << 7);  // 0..255
    const int py = ((patch >> 4) << 3), px = ((patch & 15) << 3);
    const int ty = min(max(py - 3, 0), HH - 14);
    const int tx = min(max(px - 4, 0), WW - 16);

    const float* xn = x + ((size_t)n << 20);  // n * 64ch * 16384
    const float* offn = off + n * (2 * KNN * HW);

    // ---- fused tile load from NCHW fp32: lane = (channel-pair cp, slice u).
    // 7 steps x (2 float4 reads of channels 2cp,2cp+1 for 4 pixels) ->
    // pack bf16 pairs -> 4 ds_write_b32 into the swizzled layout.
    {
        const int cp = tid >> 3;  // 0..31 channel pair
        const int u = tid & 7;    // 0..7 pixel slice
        const float* base0 = xn + ((size_t)(2 * cp) << 14) + (ty << 7) + tx;
#pragma unroll
        for (int s = 0; s < 7; s++) {
            const int p = u * 28 + s * 4;  // 4-aligned tile pixel 0..220
            const int row = p >> 4, colq = p & 15;
            const float* s0 = base0 + (row << 7) + colq;
            float4 a = *(const float4*)s0;
            float4 bb = *(const float4*)(s0 + 16384);
            const float* av = (const float*)&a;
            const float* bv = (const float*)&bb;
#pragma unroll
            for (int j = 0; j < 4; j++) {
                const int pj = p + j;
                tile[(pj << 5) + ((((cp >> 2) ^ (pj & 7)) << 2) | (cp & 3))] =
                    pk2(av[j], bv[j]);
            }
        }
    }

    const int qy = ((wv >> 1) << 2), qx = ((wv & 1) << 2);
    const int col = l & 15;
    const int oh = py + qy + (col >> 2);
    const int ow = px + qx + (col & 3);
    const int rr = (oh << 7) + ow;
    const int qc = l >> 4;   // channel chunk index 0..3 (16B chunks)
    const int cb = qc << 3;  // channel base in halfwords

    // preload all 18 offsets (overlaps the tile load)
    float offy[KNN], offx[KNN];
#pragma unroll
    for (int kn = 0; kn < KNN; kn++) {
        offy[kn] = offn[(2 * kn) * HW + rr];
        offx[kn] = offn[(2 * kn + 1) * HW + rr];
    }

    __syncthreads();  // tile resident

    const bf16x8* wfv = (const bf16x8*)wf;
    f32x4 acc[4] = {{0, 0, 0, 0}, {0, 0, 0, 0}, {0, 0, 0, 0}, {0, 0, 0, 0}};

#pragma unroll
    for (int kn = 0; kn < KNN; kn++) {
        float iy = (float)oh + offy[kn], ix = (float)ow + offx[kn];
        float y0f = floorf(iy), x0f = floorf(ix);
        float wy1 = iy - y0f, wy0 = 1.f - wy1;
        float wx1 = ix - x0f, wx0 = 1.f - wx1;
        float my0 = (y0f >= 0.f && y0f <= 127.f) ? 1.f : 0.f;
        float my1 = (y0f >= -1.f && y0f <= 126.f) ? 1.f : 0.f;
        float mx0 = (x0f >= 0.f && x0f <= 127.f) ? 1.f : 0.f;
        float mx1 = (x0f >= -1.f && x0f <= 126.f) ? 1.f : 0.f;
        float ax = wx0 * mx0, bx = wx1 * mx1;
        float cy = wy0 * my0, dy = wy1 * my1;
        int y0 = min(max((int)y0f, 0), 127), y1 = min(max((int)y0f + 1, 0), 127);
        int x0 = min(max((int)x0f, 0), 127), x1 = min(max((int)x0f + 1, 0), 127);

        const int dy0 = min(max(y0 - ty, 0), 13), dy1 = min(max(y1 - ty, 0), 13);
        const int dx0 = min(max(x0 - tx, 0), 15), dx1 = min(max(x1 - tx, 0), 15);
        const int P0 = (dy0 << 4) + dx0, P1 = (dy0 << 4) + dx1;
        const int P2 = (dy1 << 4) + dx0, P3 = (dy1 << 4) + dx1;
        const bool oot = (y0 < ty) | (y1 > ty + 13) | (x0 < tx) | (x1 > tx + 15);

        // 8 ds_read_b128: 4 corners x 2 channel-chunks (q = qc, qc+4), swizzled
        uint4 C0 = *(const uint4*)&tile[(P0 << 5) + (((qc    ) ^ (P0 & 7)) << 2)];
        uint4 C1 = *(const uint4*)&tile[(P1 << 5) + (((qc    ) ^ (P1 & 7)) << 2)];
        uint4 C2 = *(const uint4*)&tile[(P2 << 5) + (((qc    ) ^ (P2 & 7)) << 2)];
        uint4 C3 = *(const uint4*)&tile[(P3 << 5) + (((qc    ) ^ (P3 & 7)) << 2)];
        uint4 D0 = *(const uint4*)&tile[(P0 << 5) + (((qc + 4) ^ (P0 & 7)) << 2)];
        uint4 D1 = *(const uint4*)&tile[(P1 << 5) + (((qc + 4) ^ (P1 & 7)) << 2)];
        uint4 D2 = *(const uint4*)&tile[(P2 << 5) + (((qc + 4) ^ (P2 & 7)) << 2)];
        uint4 D3 = *(const uint4*)&tile[(P3 << 5) + (((qc + 4) ^ (P3 & 7)) << 2)];

        if (oot) {  // rare: exact fp32 gather from NCHW x (tile margin exceeded)
            const int g00 = (y0 << 7) + x0, g01 = (y0 << 7) + x1;
            const int g10 = (y1 << 7) + x0, g11 = (y1 << 7) + x1;
            union { u32 u[4]; uint4 v; } t0, t1, t2, t3, s0, s1, s2, s3;
#pragma unroll
            for (int t = 0; t < 4; t++) {
                const float* pc0 = xn + ((size_t)(cb + 2 * t) << 14);
                const float* pc1 = xn + ((size_t)(cb + 2 * t + 1) << 14);
                t0.u[t] = pk2(pc0[g00], pc1[g00]);
                t1.u[t] = pk2(pc0[g01], pc1[g01]);
                t2.u[t] = pk2(pc0[g10], pc1[g10]);
                t3.u[t] = pk2(pc0[g11], pc1[g11]);
                const float* qc0 = pc0 + ((size_t)32 << 14);
                const float* qc1 = pc1 + ((size_t)32 << 14);
                s0.u[t] = pk2(qc0[g00], qc1[g00]);
                s1.u[t] = pk2(qc0[g01], qc1[g01]);
                s2.u[t] = pk2(qc0[g10], qc1[g10]);
                s3.u[t] = pk2(qc0[g11], qc1[g11]);
            }
            C0 = t0.v; C1 = t1.v; C2 = t2.v; C3 = t3.v;
            D0 = s0.v; D1 = s1.v; D2 = s2.v; D3 = s3.v;
        }

#pragma unroll
        for (int cc = 0; cc < 2; cc++) {
            const u32* q0 = (const u32*)(cc ? &D0 : &C0);
            const u32* q1 = (const u32*)(cc ? &D1 : &C1);
            const u32* q2 = (const u32*)(cc ? &D2 : &C2);
            const u32* q3 = (const u32*)(cc ? &D3 : &C3);
            union { u32 u[4]; bf16x8 v; } B;
#pragma unroll
            for (int k = 0; k < 4; k++) {
                float2 e0 = up2v(q0[k]), e1 = up2v(q1[k]);
                float2 e2 = up2v(q2[k]), e3 = up2v(q3[k]);
                float2 h0, h1, s;
                h0.x = fmaf(e1.x, bx, e0.x * ax);
                h0.y = fmaf(e1.y, bx, e0.y * ax);
                h1.x = fmaf(e3.x, bx, e2.x * ax);
                h1.y = fmaf(e3.y, bx, e2.y * ax);
                s.x = fmaf(h1.x, dy, h0.x * cy);
                s.y = fmaf(h1.y, dy, h0.y * cy);
                B.u[k] = pkrn(s);
            }
#pragma unroll
            for (int s4 = 0; s4 < 4; s4++) {
                bf16x8 A = wfv[((((kn << 1) + cc) << 2) + s4) * 64 + l];
                acc[s4] = __builtin_amdgcn_mfma_f32_16x16x32_bf16(A, B.v, acc[s4], 0, 0, 0);
            }
        }
    }

    // epilogue: D layout col(pixel)=l&15, row(oc-in-strip)=(l>>4)*4+reg
    const int rq = l >> 4;
    float* op = out + ((size_t)(n * OCH) << 14);
#pragma unroll
    for (int s = 0; s < 4; s++) {
        const int ocb = (s << 4) + (rq << 2);
#pragma unroll
        for (int g = 0; g < 4; g++) {
            op[((ocb + g) << 14) + rr] = acc[s][g];
        }
    }
}

// ---- fallback (ws too small): round-1 style direct kernel
__global__ __launch_bounds__(256) void dcn_fallback_kernel(
    const float* __restrict__ x, const float* __restrict__ off,
    const float* __restrict__ w, float* __restrict__ out) {
    int p = blockIdx.x * blockDim.x + threadIdx.x;
    int n = p / HW, r = p % HW, oh = r / WW, ow = r % WW;
    float acc[OCH];
#pragma unroll
    for (int i = 0; i < OCH; i++) acc[i] = 0.f;
    const float* xn = x + n * (CI * HW);
    const float* offn = off + n * (2 * KNN * HW);
    for (int kn = 0; kn < KNN; kn++) {
        float iy = (float)oh + offn[(2 * kn) * HW + r];
        float ix = (float)ow + offn[(2 * kn + 1) * HW + r];
        float y0f = floorf(iy), x0f = floorf(ix);
        float wy1 = iy - y0f, wy0 = 1.f - wy1, wx1 = ix - x0f, wx0 = 1.f - wx1;
        float my0 = (y0f >= 0.f && y0f <= 127.f) ? 1.f : 0.f;
        float my1 = (y0f >= -1.f && y0f <= 126.f) ? 1.f : 0.f;
        float mx0 = (x0f >= 0.f && x0f <= 127.f) ? 1.f : 0.f;
        float mx1 = (x0f >= -1.f && x0f <= 126.f) ? 1.f : 0.f;
        float w00 = wy0 * wx0 * my0 * mx0, w01 = wy0 * wx1 * my0 * mx1;
        float w10 = wy1 * wx0 * my1 * mx0, w11 = wy1 * wx1 * my1 * mx1;
        int y0 = min(max((int)y0f, 0), 127), y1 = min(max((int)y0f + 1, 0), 127);
        int x0 = min(max((int)x0f, 0), 127), x1 = min(max((int)x0f + 1, 0), 127);
        int o00 = y0 * WW + x0, o01 = y0 * WW + x1, o10 = y1 * WW + x0, o11 = y1 * WW + x1;
        for (int c = 0; c < CI; c++) {
            const float* xc = xn + c * HW;
            float s = xc[o00] * w00 + xc[o01] * w01 + xc[o10] * w10 + xc[o11] * w11;
#pragma unroll
            for (int oc = 0; oc < OCH; oc++) acc[oc] += w[(oc * CI + c) * KNN + kn] * s;
        }
    }
    float* outp = out + n * (OCH * HW) + r;
#pragma unroll
    for (int oc = 0; oc < OCH; oc++) outp[oc * HW] = acc[oc];
}

extern "C" void kernel_launch(void* const* d_in, const int* in_sizes, int n_in,
                              void* d_out, int out_size, void* d_ws, size_t ws_size,
                              hipStream_t stream) {
    const float* x = (const float*)d_in[0];
    const float* off = (const float*)d_in[1];
    const float* w = (const float*)d_in[2];
    float* out = (float*)d_out;

    const size_t wf_elems = (size_t)KNN * 2 * 4 * 64 * 8;  // 36,864 u16
    const size_t need = wf_elems * sizeof(u16);            // 73,728 B

    if (ws_size >= need) {
        u16* wfr = (u16*)d_ws;
        wf_prep_kernel<<<(int)((wf_elems + 255) / 256), 256, 0, stream>>>(w, wfr);
        dcn_main_kernel<<<NB * 256, 256, 0, stream>>>(x, off, wfr, out);
    } else {
        dcn_fallback_kernel<<<(NB * HW) / 256, 256, 0, stream>>>(x, off, w, out);
    }
}